// Round 7
// baseline (989.934 us; speedup 1.0000x reference)
//
#include <hip/hip_runtime.h>

#define IH 126
#define IW 126
#define HW 15876      // 126*126
#define OH 124
#define OW 124
#define OHW 15376     // 124*124

// All intermediate tensors live in [pixel][channel] layout: t[pos*64 + c].

// ---------------------------------------------------------------- conv_in
// (1,3,128,128) -> y_t[pos][64]. Weights via LDS broadcast (wave-uniform oc).
__global__ __launch_bounds__(256) void conv_in_kernel(
    const float* __restrict__ x, const float* __restrict__ w,
    const float* __restrict__ b, float* __restrict__ yt)
{
  __shared__ float wl[64 * 28];   // [oc][27+pad]
  __shared__ float bl[64];
  int tid = threadIdx.x;
  for (int i = tid; i < 1728; i += 256) {
    int oc = i / 27, r = i - oc * 27;
    wl[oc * 28 + r] = w[i];
  }
  if (tid < 64) bl[tid] = b[tid];
  __syncthreads();

  int pix = blockIdx.x * 256 + tid;
  if (pix >= HW) return;
  int h = pix / IW;
  int wc = pix - h * IW;
  float xr[27];
#pragma unroll
  for (int ci = 0; ci < 3; ci++)
#pragma unroll
    for (int ky = 0; ky < 3; ky++)
#pragma unroll
      for (int kx = 0; kx < 3; kx++)
        xr[ci * 9 + ky * 3 + kx] = x[ci * 128 * 128 + (h + ky) * 128 + (wc + kx)];

  float* yp = yt + pix * 64;
#pragma unroll 1
  for (int oc4 = 0; oc4 < 64; oc4 += 4) {
    float4 o;
    float* op = (float*)&o;
#pragma unroll
    for (int j = 0; j < 4; j++) {
      const float* wp = &wl[(oc4 + j) * 28];   // wave-uniform -> broadcast
      float a = bl[oc4 + j];
#pragma unroll
      for (int i = 0; i < 27; i++) a = fmaf(xr[i], wp[i], a);
      op[j] = a;
    }
    *(float4*)(yp + oc4) = o;
  }
}

// ---------------------------------------------------------------- involution v6
// [pos][ch] I/O. Tile 8x4, 512 thr, grid 512.
//   A: wave-uniform pos, lane=ch: coalesced 256B load + stride-1 LDS write.
//   B: t = ReLU(BN(Wr.x)), wave-uniform cr pair -> s_load weights.
//   C: span, wave-uniform pairs -> s_load_dwordx16.
//   D: einsum, lane=ch: xs reads stride-1 (free), wvs skewed 4-quad b128.
//   E: direct coalesced global stores (lane=ch), no LDS, no barrier.
__global__ __launch_bounds__(512, 4) void inv_kernel(
    const float* __restrict__ xt, float* __restrict__ yt,
    const float* __restrict__ wr, const float* __restrict__ br,
    const float* __restrict__ gam, const float* __restrict__ bet,
    const float* __restrict__ mu, const float* __restrict__ var,
    const float* __restrict__ wspan, const float* __restrict__ bspan)
{
  __shared__ __align__(16) float xs[140 * 65];   // 36,400 B [pos][ch+pad]
  __shared__ __align__(16) float wvs[6296];      // 25,184 B skewed pair*32+g*8
  __shared__ float bsp_l[196];                   //    784 B
  float* tss = &wvs[5656];                       // [32][20] overlap tail

  int tid = threadIdx.x;
  int bx = blockIdx.x & 15, by = blockIdx.x >> 4;
  int ox0 = bx * 8, oy0 = by * 4;
  int xh0 = ox0 - 3, yh0 = oy0 - 3;

  int w_ = __builtin_amdgcn_readfirstlane(tid >> 6);  // wave 0..7
  int ln = tid & 63;

  // ---- Phase A: stage halo (14x10 pos x 64 ch) + bspan
  if (tid < 196) bsp_l[tid] = bspan[tid];
  for (int pos = w_; pos < 140; pos += 8) {      // pos wave-uniform
    int r = pos / 14;                            // scalar math
    int cc = pos - r * 14;
    int gy = yh0 + r, gx = xh0 + cc;
    float v = 0.f;
    if (gy >= 0 && gy < IH && gx >= 0 && gx < IW)   // uniform branch
      v = xt[(gy * IW + gx) * 64 + ln];             // coalesced 256B
    xs[pos * 65 + ln] = v;                          // stride-1: conflict-free
  }
  __syncthreads();

  int p  = ln & 31;                   // pixel 0..31 (upper half duplicates)
  int prow = p >> 3, pcol = p & 7;
  int pc = (prow + 3) * 14 + (pcol + 3);

  // ---- Phase B: t = ReLU(BN(Wr.x)); wave w_ does cr = 2w_, 2w_+1 (uniform)
  {
    int cr0 = 2 * w_;
    const float* wa = wr + cr0 * 64;  // uniform -> s_load
    const float* wb = wa + 64;
    float a0 = 0.f, a1 = 0.f;
#pragma unroll
    for (int ci = 0; ci < 64; ci++) {
      float xv = xs[pc * 65 + ci];    // lanes: 32 distinct pc, ~2-way: free
      a0 = fmaf(xv, wa[ci], a0);
      a1 = fmaf(xv, wb[ci], a1);
    }
    float s0 = gam[cr0]     * rsqrtf(var[cr0]     + 1e-5f);
    float s1 = gam[cr0 + 1] * rsqrtf(var[cr0 + 1] + 1e-5f);
    float t0 = (a0 + br[cr0]     - mu[cr0])     * s0 + bet[cr0];
    float t1 = (a1 + br[cr0 + 1] - mu[cr0 + 1]) * s1 + bet[cr0 + 1];
    if (ln < 32) {
      tss[p * 20 + cr0]     = fmaxf(t0, 0.f);
      tss[p * 20 + cr0 + 1] = fmaxf(t1, 0.f);
    }
  }
  __syncthreads();

  // ---- Phase C: span. wave w_ owns uniform pairs (g*49+k) = w_ + 8j.
  {
    float tv[16];
#pragma unroll
    for (int i = 0; i < 4; i++) {
      float4 t4 = *(const float4*)&tss[p * 20 + 4 * i];
      tv[4 * i] = t4.x; tv[4 * i + 1] = t4.y;
      tv[4 * i + 2] = t4.z; tv[4 * i + 3] = t4.w;
    }
    __syncthreads();                   // tv in regs; tail region reusable
#pragma unroll
    for (int j = 0; j < 24; j++) {
      int pair = w_ + 8 * j;           // wave-uniform
      int gc = (pair * 669) >> 15;     // pair/49
      const float* wk = wspan + pair * 16;   // uniform -> s_load_dwordx16
      float a = bsp_l[pair];
#pragma unroll
      for (int i = 0; i < 16; i++) a = fmaf(tv[i], wk[i], a);
      if (ln < 32) wvs[pair * 32 + gc * 8 + pcol * 4 + prow] = a;
    }
    if (w_ < 4) {                      // tail: pair 192..195 (gc=3)
      int pair = w_ + 192;
      const float* wk = wspan + pair * 16;
      float a = bsp_l[pair];
#pragma unroll
      for (int i = 0; i < 16; i++) a = fmaf(tv[i], wk[i], a);
      if (ln < 32) wvs[pair * 32 + 24 + pcol * 4 + prow] = a;
    }
  }
  __syncthreads();

  // ---- Phase D: einsum. wave = output column w_, lane = channel.
  float acc0 = 0.f, acc1 = 0.f, acc2 = 0.f, acc3 = 0.f;
  {
    int gb = (ln >> 4) * 1576;         // g*(49*32+8): 4 distinct quad-banks
    float xw[4][7];
#pragma unroll
    for (int r = 0; r < 4; r++)
#pragma unroll
      for (int kx = 0; kx < 7; kx++)
        xw[r][kx] = xs[(r * 14 + w_ + kx) * 65 + ln];   // stride-1: free
#pragma unroll
    for (int ky = 0; ky < 7; ky++) {
      if (ky > 0) {
#pragma unroll
        for (int r = 0; r < 3; r++)
#pragma unroll
          for (int kx = 0; kx < 7; kx++) xw[r][kx] = xw[r + 1][kx];
#pragma unroll
        for (int kx = 0; kx < 7; kx++)
          xw[3][kx] = xs[((ky + 3) * 14 + w_ + kx) * 65 + ln];
      }
#pragma unroll
      for (int kx = 0; kx < 7; kx++) {
        int k = ky * 7 + kx;
        float4 w4 = *(const float4*)&wvs[gb + k * 32 + w_ * 4];
        acc0 = fmaf(w4.x, xw[0][kx], acc0);
        acc1 = fmaf(w4.y, xw[1][kx], acc1);
        acc2 = fmaf(w4.z, xw[2][kx], acc2);
        acc3 = fmaf(w4.w, xw[3][kx], acc3);
      }
    }
  }

  // ---- Phase E: direct coalesced stores (+outer ReLU), no LDS
  {
    int gx = ox0 + w_;
    if (gx < IW) {
      if (oy0 + 0 < IH) yt[((oy0 + 0) * IW + gx) * 64 + ln] = fmaxf(acc0, 0.f);
      if (oy0 + 1 < IH) yt[((oy0 + 1) * IW + gx) * 64 + ln] = fmaxf(acc1, 0.f);
      if (oy0 + 2 < IH) yt[((oy0 + 2) * IW + gx) * 64 + ln] = fmaxf(acc2, 0.f);
      if (oy0 + 3 < IH) yt[((oy0 + 3) * IW + gx) * 64 + ln] = fmaxf(acc3, 0.f);
    }
  }
}

// ---------------------------------------------------------------- conv_out prep
// w (128,64,3,3) -> wt[k][ci][oc] (v3 layout)
__global__ __launch_bounds__(256) void transpose_w_kernel(
    const float* __restrict__ w, float* __restrict__ wt)
{
  int i = blockIdx.x * 256 + threadIdx.x;
  if (i >= 128 * 64 * 9) return;
  int oc = i / 576;
  int rem = i - oc * 576;
  int ci = rem / 9;
  int k = rem - ci * 9;
  wt[(k * 64 + ci) * 128 + oc] = w[i];
}

// ---------------------------------------------------------------- conv_out v8
// v3's proven compute core (45 µs: 8x8 tile, 8 oc/thread, lane-consecutive
// 16B LDS reads, wave-uniform oc -> s_load weights) with cheap staging from
// the [pos][ch] layout: one b128 global read per LDS b128 write.
__global__ __launch_bounds__(256) void conv_out_kernel(
    const float* __restrict__ xt, const float* __restrict__ wt,
    const float* __restrict__ b, float* __restrict__ y)
{
  __shared__ __align__(16) float xsm[16 * 100 * 4];   // 25,600 B [cq][pos][4]
  int tid = threadIdx.x;
  int bx = blockIdx.x & 15, by = blockIdx.x >> 4;
  int oy0 = by * 8, ox0 = bx * 8;

  for (int u = tid; u < 1600; u += 256) {
    int cq = u / 100;
    int pos = u - cq * 100;
    int row = pos / 10;
    int col = pos - row * 10;
    int gy = oy0 + row, gx = ox0 + col;
    float4 v = make_float4(0.f, 0.f, 0.f, 0.f);
    if (gy < IH && gx < IW)
      v = *(const float4*)&xt[(gy * IW + gx) * 64 + cq * 4];
    *(float4*)&xsm[u * 4] = v;
  }
  __syncthreads();

  int ln = tid & 63;
  int px = ln & 7, py = ln >> 3;
  int wv_ = __builtin_amdgcn_readfirstlane(tid >> 6);   // wave 0..3
  int oc8 = blockIdx.y * 32 + wv_ * 8;

  float acc[8];
#pragma unroll
  for (int j = 0; j < 8; j++) acc[j] = b[oc8 + j];

#pragma unroll
  for (int ky = 0; ky < 3; ky++) {
#pragma unroll
    for (int kx = 0; kx < 3; kx++) {
      int k = ky * 3 + kx;
      int pidx = (py + ky) * 10 + px + kx;
      const float* wp = wt + k * 64 * 128 + oc8;   // uniform -> s_loads
#pragma unroll 4
      for (int cq = 0; cq < 16; cq++) {
        float4 xv = *(const float4*)&xsm[(cq * 100 + pidx) * 4];
        const float* wq = wp + cq * 4 * 128;
#pragma unroll
        for (int j = 0; j < 8; j++) {
          acc[j] = fmaf(xv.x, wq[0 * 128 + j], acc[j]);
          acc[j] = fmaf(xv.y, wq[1 * 128 + j], acc[j]);
          acc[j] = fmaf(xv.z, wq[2 * 128 + j], acc[j]);
          acc[j] = fmaf(xv.w, wq[3 * 128 + j], acc[j]);
        }
      }
    }
  }

  int oy = oy0 + py, ox = ox0 + px;
  if (oy < OH && ox < OW) {
#pragma unroll
    for (int j = 0; j < 8; j++)
      y[(oc8 + j) * OHW + oy * OW + ox] = acc[j];
  }
}

// ---------------------------------------------------------------- launch
extern "C" void kernel_launch(void* const* d_in, const int* in_sizes, int n_in,
                              void* d_out, int out_size, void* d_ws, size_t ws_size,
                              hipStream_t stream)
{
  const float* input = (const float*)d_in[0];
  const float* ciw   = (const float*)d_in[1];
  const float* cib   = (const float*)d_in[2];
  const float* wred  = (const float*)d_in[3];
  const float* bred  = (const float*)d_in[4];
  const float* gam   = (const float*)d_in[5];
  const float* bet   = (const float*)d_in[6];
  const float* mu    = (const float*)d_in[7];
  const float* var   = (const float*)d_in[8];
  const float* wspan = (const float*)d_in[9];
  const float* bspan = (const float*)d_in[10];
  const float* cow   = (const float*)d_in[11];
  const float* cob   = (const float*)d_in[12];
  float* out = (float*)d_out;

  float* bufA = (float*)d_ws;                 // x_t: 15876*64 = 1,016,064 floats
  float* bufB = bufA + (1 << 20);             // @ 4 MiB
  float* wt   = bufA + (1 << 21);             // @ 8 MiB

  transpose_w_kernel<<<288, 256, 0, stream>>>(cow, wt);
  conv_in_kernel<<<63, 256, 0, stream>>>(input, ciw, cib, bufA);

  float* cur = bufA; float* nxt = bufB;
  for (int i = 0; i < 6; i++) {
    inv_kernel<<<512, 512, 0, stream>>>(cur, nxt,
        wred + i * 16 * 64, bred + i * 16, gam + i * 16, bet + i * 16,
        mu + i * 16, var + i * 16, wspan + i * 196 * 16, bspan + i * 196);
    float* t = cur; cur = nxt; nxt = t;
  }
  conv_out_kernel<<<dim3(256, 4), 256, 0, stream>>>(cur, wt, cob, out);
}

// Round 8
// 289.820 us; speedup vs baseline: 3.4157x; 3.4157x over previous
//
#include <hip/hip_runtime.h>

#define IH 126
#define IW 126
#define HW 15876      // 126*126
#define OH 124
#define OW 124
#define OHW 15376     // 124*124

// All intermediate tensors live in [pixel][channel] layout: t[pos*64 + c].

// ---------------------------------------------------------------- conv_in
// (1,3,128,128) -> y_t[pos][64]. Weights via LDS broadcast (wave-uniform oc).
__global__ __launch_bounds__(256) void conv_in_kernel(
    const float* __restrict__ x, const float* __restrict__ w,
    const float* __restrict__ b, float* __restrict__ yt)
{
  __shared__ float wl[64 * 28];   // [oc][27+pad]
  __shared__ float bl[64];
  int tid = threadIdx.x;
  for (int i = tid; i < 1728; i += 256) {
    int oc = i / 27, r = i - oc * 27;
    wl[oc * 28 + r] = w[i];
  }
  if (tid < 64) bl[tid] = b[tid];
  __syncthreads();

  int pix = blockIdx.x * 256 + tid;
  if (pix >= HW) return;
  int h = pix / IW;
  int wc = pix - h * IW;
  float xr[27];
#pragma unroll
  for (int ci = 0; ci < 3; ci++)
#pragma unroll
    for (int ky = 0; ky < 3; ky++)
#pragma unroll
      for (int kx = 0; kx < 3; kx++)
        xr[ci * 9 + ky * 3 + kx] = x[ci * 128 * 128 + (h + ky) * 128 + (wc + kx)];

  float* yp = yt + pix * 64;
#pragma unroll 1
  for (int oc4 = 0; oc4 < 64; oc4 += 4) {
    float4 o;
    float* op = (float*)&o;
#pragma unroll
    for (int j = 0; j < 4; j++) {
      const float* wp = &wl[(oc4 + j) * 28];   // wave-uniform -> broadcast
      float a = bl[oc4 + j];
#pragma unroll
      for (int i = 0; i < 27; i++) a = fmaf(xr[i], wp[i], a);
      op[j] = a;
    }
    *(float4*)(yp + oc4) = o;
  }
}

// ---------------------------------------------------------------- involution v7
// v6 structure, launch bounds FIXED: (512,4) capped VGPRs at 64 and spilled
// ~1.9 KB/thread to scratch (273 MB FETCH + 201 MB WRITE per dispatch, r7
// counters). (512,2) -> cap >=128 VGPR; LDS (62 KB) already limits occupancy
// to 2 blocks/CU, so the lower min-waves request costs nothing.
__global__ __launch_bounds__(512, 2) void inv_kernel(
    const float* __restrict__ xt, float* __restrict__ yt,
    const float* __restrict__ wr, const float* __restrict__ br,
    const float* __restrict__ gam, const float* __restrict__ bet,
    const float* __restrict__ mu, const float* __restrict__ var,
    const float* __restrict__ wspan, const float* __restrict__ bspan)
{
  __shared__ __align__(16) float xs[140 * 65];   // 36,400 B [pos][ch+pad]
  __shared__ __align__(16) float wvs[6296];      // 25,184 B skewed pair*32+g*8
  __shared__ float bsp_l[196];                   //    784 B
  float* tss = &wvs[5656];                       // [32][20] overlap tail

  int tid = threadIdx.x;
  int bx = blockIdx.x & 15, by = blockIdx.x >> 4;
  int ox0 = bx * 8, oy0 = by * 4;
  int xh0 = ox0 - 3, yh0 = oy0 - 3;

  int w_ = __builtin_amdgcn_readfirstlane(tid >> 6);  // wave 0..7
  int ln = tid & 63;

  // ---- Phase A: stage halo (14x10 pos x 64 ch) + bspan
  if (tid < 196) bsp_l[tid] = bspan[tid];
  for (int pos = w_; pos < 140; pos += 8) {      // pos wave-uniform
    int r = pos / 14;                            // scalar math
    int cc = pos - r * 14;
    int gy = yh0 + r, gx = xh0 + cc;
    float v = 0.f;
    if (gy >= 0 && gy < IH && gx >= 0 && gx < IW)   // uniform branch
      v = xt[(gy * IW + gx) * 64 + ln];             // coalesced 256B
    xs[pos * 65 + ln] = v;                          // stride-1: conflict-free
  }
  __syncthreads();

  int p  = ln & 31;                   // pixel 0..31 (upper half duplicates)
  int prow = p >> 3, pcol = p & 7;
  int pc = (prow + 3) * 14 + (pcol + 3);

  // ---- Phase B: t = ReLU(BN(Wr.x)); wave w_ does cr = 2w_, 2w_+1 (uniform)
  {
    int cr0 = 2 * w_;
    const float* wa = wr + cr0 * 64;  // uniform -> s_load
    const float* wb = wa + 64;
    float a0 = 0.f, a1 = 0.f;
#pragma unroll
    for (int ci = 0; ci < 64; ci++) {
      float xv = xs[pc * 65 + ci];    // lanes: 32 distinct pc, ~2-way: free
      a0 = fmaf(xv, wa[ci], a0);
      a1 = fmaf(xv, wb[ci], a1);
    }
    float s0 = gam[cr0]     * rsqrtf(var[cr0]     + 1e-5f);
    float s1 = gam[cr0 + 1] * rsqrtf(var[cr0 + 1] + 1e-5f);
    float t0 = (a0 + br[cr0]     - mu[cr0])     * s0 + bet[cr0];
    float t1 = (a1 + br[cr0 + 1] - mu[cr0 + 1]) * s1 + bet[cr0 + 1];
    if (ln < 32) {
      tss[p * 20 + cr0]     = fmaxf(t0, 0.f);
      tss[p * 20 + cr0 + 1] = fmaxf(t1, 0.f);
    }
  }
  __syncthreads();

  // ---- Phase C: span. wave w_ owns uniform pairs (g*49+k) = w_ + 8j.
  {
    float tv[16];
#pragma unroll
    for (int i = 0; i < 4; i++) {
      float4 t4 = *(const float4*)&tss[p * 20 + 4 * i];
      tv[4 * i] = t4.x; tv[4 * i + 1] = t4.y;
      tv[4 * i + 2] = t4.z; tv[4 * i + 3] = t4.w;
    }
    __syncthreads();                   // tv in regs; tail region reusable
#pragma unroll
    for (int j = 0; j < 24; j++) {
      int pair = w_ + 8 * j;           // wave-uniform
      int gc = (pair * 669) >> 15;     // pair/49
      const float* wk = wspan + pair * 16;   // uniform -> s_load_dwordx16
      float a = bsp_l[pair];
#pragma unroll
      for (int i = 0; i < 16; i++) a = fmaf(tv[i], wk[i], a);
      if (ln < 32) wvs[pair * 32 + gc * 8 + pcol * 4 + prow] = a;
    }
    if (w_ < 4) {                      // tail: pair 192..195 (gc=3)
      int pair = w_ + 192;
      const float* wk = wspan + pair * 16;
      float a = bsp_l[pair];
#pragma unroll
      for (int i = 0; i < 16; i++) a = fmaf(tv[i], wk[i], a);
      if (ln < 32) wvs[pair * 32 + 24 + pcol * 4 + prow] = a;
    }
  }
  __syncthreads();

  // ---- Phase D: einsum. wave = output column w_, lane = channel.
  float acc0 = 0.f, acc1 = 0.f, acc2 = 0.f, acc3 = 0.f;
  {
    int gb = (ln >> 4) * 1576;         // g*(49*32+8): 4 distinct quad-banks
    float xw[4][7];
#pragma unroll
    for (int r = 0; r < 4; r++)
#pragma unroll
      for (int kx = 0; kx < 7; kx++)
        xw[r][kx] = xs[(r * 14 + w_ + kx) * 65 + ln];   // stride-1: free
#pragma unroll
    for (int ky = 0; ky < 7; ky++) {
      if (ky > 0) {
#pragma unroll
        for (int r = 0; r < 3; r++)
#pragma unroll
          for (int kx = 0; kx < 7; kx++) xw[r][kx] = xw[r + 1][kx];
#pragma unroll
        for (int kx = 0; kx < 7; kx++)
          xw[3][kx] = xs[((ky + 3) * 14 + w_ + kx) * 65 + ln];
      }
#pragma unroll
      for (int kx = 0; kx < 7; kx++) {
        int k = ky * 7 + kx;
        float4 w4 = *(const float4*)&wvs[gb + k * 32 + w_ * 4];
        acc0 = fmaf(w4.x, xw[0][kx], acc0);
        acc1 = fmaf(w4.y, xw[1][kx], acc1);
        acc2 = fmaf(w4.z, xw[2][kx], acc2);
        acc3 = fmaf(w4.w, xw[3][kx], acc3);
      }
    }
  }

  // ---- Phase E: direct coalesced stores (+outer ReLU), no LDS
  {
    int gx = ox0 + w_;
    if (gx < IW) {
      if (oy0 + 0 < IH) yt[((oy0 + 0) * IW + gx) * 64 + ln] = fmaxf(acc0, 0.f);
      if (oy0 + 1 < IH) yt[((oy0 + 1) * IW + gx) * 64 + ln] = fmaxf(acc1, 0.f);
      if (oy0 + 2 < IH) yt[((oy0 + 2) * IW + gx) * 64 + ln] = fmaxf(acc2, 0.f);
      if (oy0 + 3 < IH) yt[((oy0 + 3) * IW + gx) * 64 + ln] = fmaxf(acc3, 0.f);
    }
  }
}

// ---------------------------------------------------------------- conv_out prep
// w (128,64,3,3) -> wt[k][ci][oc] (v3 layout)
__global__ __launch_bounds__(256) void transpose_w_kernel(
    const float* __restrict__ w, float* __restrict__ wt)
{
  int i = blockIdx.x * 256 + threadIdx.x;
  if (i >= 128 * 64 * 9) return;
  int oc = i / 576;
  int rem = i - oc * 576;
  int ci = rem / 9;
  int k = rem - ci * 9;
  wt[(k * 64 + ci) * 128 + oc] = w[i];
}

// ---------------------------------------------------------------- conv_out v8
// v3's compute core (8x8 tile, 8 oc/thread, wave-uniform oc -> s_load weights)
// with cheap staging from [pos][ch]: one b128 global read per LDS b128 write.
__global__ __launch_bounds__(256) void conv_out_kernel(
    const float* __restrict__ xt, const float* __restrict__ wt,
    const float* __restrict__ b, float* __restrict__ y)
{
  __shared__ __align__(16) float xsm[16 * 100 * 4];   // 25,600 B [cq][pos][4]
  int tid = threadIdx.x;
  int bx = blockIdx.x & 15, by = blockIdx.x >> 4;
  int oy0 = by * 8, ox0 = bx * 8;

  for (int u = tid; u < 1600; u += 256) {
    int cq = u / 100;
    int pos = u - cq * 100;
    int row = pos / 10;
    int col = pos - row * 10;
    int gy = oy0 + row, gx = ox0 + col;
    float4 v = make_float4(0.f, 0.f, 0.f, 0.f);
    if (gy < IH && gx < IW)
      v = *(const float4*)&xt[(gy * IW + gx) * 64 + cq * 4];
    *(float4*)&xsm[u * 4] = v;
  }
  __syncthreads();

  int ln = tid & 63;
  int px = ln & 7, py = ln >> 3;
  int wv_ = __builtin_amdgcn_readfirstlane(tid >> 6);   // wave 0..3
  int oc8 = blockIdx.y * 32 + wv_ * 8;

  float acc[8];
#pragma unroll
  for (int j = 0; j < 8; j++) acc[j] = b[oc8 + j];

#pragma unroll
  for (int ky = 0; ky < 3; ky++) {
#pragma unroll
    for (int kx = 0; kx < 3; kx++) {
      int k = ky * 3 + kx;
      int pidx = (py + ky) * 10 + px + kx;
      const float* wp = wt + k * 64 * 128 + oc8;   // uniform -> s_loads
#pragma unroll 4
      for (int cq = 0; cq < 16; cq++) {
        float4 xv = *(const float4*)&xsm[(cq * 100 + pidx) * 4];
        const float* wq = wp + cq * 4 * 128;
#pragma unroll
        for (int j = 0; j < 8; j++) {
          acc[j] = fmaf(xv.x, wq[0 * 128 + j], acc[j]);
          acc[j] = fmaf(xv.y, wq[1 * 128 + j], acc[j]);
          acc[j] = fmaf(xv.z, wq[2 * 128 + j], acc[j]);
          acc[j] = fmaf(xv.w, wq[3 * 128 + j], acc[j]);
        }
      }
    }
  }

  int oy = oy0 + py, ox = ox0 + px;
  if (oy < OH && ox < OW) {
#pragma unroll
    for (int j = 0; j < 8; j++)
      y[(oc8 + j) * OHW + oy * OW + ox] = acc[j];
  }
}

// ---------------------------------------------------------------- launch
extern "C" void kernel_launch(void* const* d_in, const int* in_sizes, int n_in,
                              void* d_out, int out_size, void* d_ws, size_t ws_size,
                              hipStream_t stream)
{
  const float* input = (const float*)d_in[0];
  const float* ciw   = (const float*)d_in[1];
  const float* cib   = (const float*)d_in[2];
  const float* wred  = (const float*)d_in[3];
  const float* bred  = (const float*)d_in[4];
  const float* gam   = (const float*)d_in[5];
  const float* bet   = (const float*)d_in[6];
  const float* mu    = (const float*)d_in[7];
  const float* var   = (const float*)d_in[8];
  const float* wspan = (const float*)d_in[9];
  const float* bspan = (const float*)d_in[10];
  const float* cow   = (const float*)d_in[11];
  const float* cob   = (const float*)d_in[12];
  float* out = (float*)d_out;

  float* bufA = (float*)d_ws;                 // x_t: 15876*64 = 1,016,064 floats
  float* bufB = bufA + (1 << 20);             // @ 4 MiB
  float* wt   = bufA + (1 << 21);             // @ 8 MiB

  transpose_w_kernel<<<288, 256, 0, stream>>>(cow, wt);
  conv_in_kernel<<<63, 256, 0, stream>>>(input, ciw, cib, bufA);

  float* cur = bufA; float* nxt = bufB;
  for (int i = 0; i < 6; i++) {
    inv_kernel<<<512, 512, 0, stream>>>(cur, nxt,
        wred + i * 16 * 64, bred + i * 16, gam + i * 16, bet + i * 16,
        mu + i * 16, var + i * 16, wspan + i * 196 * 16, bspan + i * 196);
    float* t = cur; cur = nxt; nxt = t;
  }
  conv_out_kernel<<<dim3(256, 4), 256, 0, stream>>>(cur, wt, cob, out);
}